// Round 10
// baseline (271.537 us; speedup 1.0000x reference)
//
#include <hip/hip_runtime.h>

// ReActNet BasicBlock forward: out = BN(binary_conv3x3(sign(x), scale*sign(w))) + x
//
// i8 MFMA implicit-GEMM, 2D-patch LDS staging:
//   sign(x) -> padded LINEAR NHWC i8 S[n][58][58][128] (r1-proven contract).
//   bconv block = 8x8 output patch (64 px), window 10x10 px = 12.8 KB LDS.
//   Staging: global_load_lds with PER-LANE inverse-swizzled global source
//   (slot' = slot ^ (px&7)), linear LDS dest; reads use the same XOR.
//   Block = 256 thr = 4 waves = 4 o-tiles; wave = 32 o x 64 px (2 chains).
//   56 = 7*8 -> 7x7 patches/image, zero tail. grid 3136 = 8*392 (XCD swz).
//   launch_bounds(256,6): 6 blocks/CU (77 KB LDS, 24 waves) for residency.

#define N_   64
#define C_   128
#define H_   56
#define W_   56
#define HW_  (H_*W_)       // 3136
#define PH_  (H_+2)        // 58
#define PW_  (W_+2)        // 58
#define PHW_ (PH_*PW_)     // 3364
#define NPIX (N_*HW_)      // 200704
#define NPAD (N_*PHW_)     // 215296
#define SBYTES ((size_t)NPAD * 128)   // 27,557,888

typedef int v4i  __attribute__((ext_vector_type(4)));
typedef int v16i __attribute__((ext_vector_type(16)));

__device__ __forceinline__ void glds16(const char* g, char* l) {
    __builtin_amdgcn_global_load_lds(
        (const __attribute__((address_space(1))) void*)g,
        (__attribute__((address_space(3))) void*)l, 16, 0, 0);
}

__device__ __forceinline__ unsigned sign_byte(unsigned u) {
    // {+1, 0 (exact zero incl -0.0), 0xFF}
    return ((u << 1) == 0u) ? 0u : ((u >> 31) ? 0xFFu : 1u);
}

// ---------------------------------------------------------------------------
// Kernel 1: fused weight prep (r8-proven). One 64-thread block per channel o.
// ---------------------------------------------------------------------------
__global__ void prep_w_kernel(const float* __restrict__ w,
                              const float* __restrict__ gamma,
                              const float* __restrict__ beta,
                              const float* __restrict__ bn_mean,
                              const float* __restrict__ bn_var,
                              v4i* __restrict__ wfrag,
                              float2* __restrict__ AB) {
    const int o = blockIdx.x;
    const int lane = threadIdx.x;          // 0..63
    const float* wo = w + o * 1152;

    float s = 0.f;
    #pragma unroll
    for (int k = 0; k < 18; k++) s += fabsf(wo[k * 64 + lane]);
    #pragma unroll
    for (int off = 32; off > 0; off >>= 1) s += __shfl_down(s, off);

    #pragma unroll
    for (int rep = 0; rep < 2; rep++) {
        int f = rep * 64 + lane;
        if (f < 72) {
            int t = f >> 3, ks = (f >> 1) & 3, lh = f & 1;
            int cbase = ks * 32 + lh * 16;
            unsigned d[4];
            #pragma unroll
            for (int i = 0; i < 4; i++) {
                unsigned wd = 0;
                #pragma unroll
                for (int j = 0; j < 4; j++) {
                    unsigned u = __float_as_uint(wo[(cbase + i * 4 + j) * 9 + t]);
                    wd |= sign_byte(u) << (8 * j);
                }
                d[i] = wd;
            }
            v4i v; v.x=(int)d[0]; v.y=(int)d[1]; v.z=(int)d[2]; v.w=(int)d[3];
            wfrag[(((o >> 5) * 9 + t) * 4 + ks) * 64 + (lh << 5) + (o & 31)] = v;
        }
    }
    if (lane == 0) {
        float scale = s * (1.0f / 1152.0f);
        float inv = gamma[o] * rsqrtf(bn_var[o] + 1e-5f);
        float2 ab; ab.x = scale * inv; ab.y = beta[o] - bn_mean[o] * inv;
        AB[o] = ab;
    }
}

// ---------------------------------------------------------------------------
// Kernel 2: binarize x into padded LINEAR NHWC i8 (r1-proven contract).
//   Border blocks (blockIdx >= 3136) zero the padded frame.
// ---------------------------------------------------------------------------
__global__ __launch_bounds__(256) void pack_s_kernel(
        const float* __restrict__ x, char* __restrict__ S) {
    const int tid = threadIdx.x;
    const int pixl = tid & 63, q = tid >> 6;      // q = channel quarter
    const int b = blockIdx.x;

    if (b >= NPIX / 64) {                          // border: 228 blocks
        int bt = (b - NPIX / 64) * 64 + pixl;      // 0..14591
        int n = bt / 228, e = bt - n * 228;
        int ph, pw;
        if (e < 58)       { ph = 0;  pw = e; }
        else if (e < 116) { ph = 57; pw = e - 58; }
        else { int i = e - 116; ph = 1 + (i >> 1); pw = (i & 1) ? 57 : 0; }
        v4i z = {};
        char* dst = S + (size_t)((n * PH_ + ph) * PW_ + pw) * 128 + q * 32;
        ((v4i*)dst)[0] = z;
        ((v4i*)dst)[1] = z;
        return;
    }

    const int g = b * 64 + pixl;                   // 0..NPIX-1
    const int n = g / HW_;
    const int p = g - n * HW_;
    const int row = p / W_, col = p - row * W_;

    const float* xp = x + ((size_t)n * C_ + q * 32) * HW_ + p;
    unsigned w[8];
    #pragma unroll
    for (int i = 0; i < 8; i++) {
        unsigned wd = 0;
        #pragma unroll
        for (int j = 0; j < 4; j++) {
            unsigned u = __float_as_uint(xp[(i * 4 + j) * HW_]);
            wd |= sign_byte(u) << (8 * j);
        }
        w[i] = wd;
    }
    char* dst = S + (size_t)((n * PH_ + row + 1) * PW_ + col + 1) * 128 + q * 32;
    v4i t0; t0.x=(int)w[0]; t0.y=(int)w[1]; t0.z=(int)w[2]; t0.w=(int)w[3];
    v4i t1; t1.x=(int)w[4]; t1.y=(int)w[5]; t1.z=(int)w[6]; t1.w=(int)w[7];
    ((v4i*)dst)[0] = t0;
    ((v4i*)dst)[1] = t1;
}

// ---------------------------------------------------------------------------
// Kernel 3: i8 MFMA conv + BN + residual, 8x8-patch LDS staging.
//   grid = 3136 = 64 images * 49 patches. bid = (b0&7)*392 + (b0>>3).
//   Window: 10x10 px, 800 chunks of 16B; 13 wave-issues (wave wid takes
//   j%4==wid), chunks >= 800 clamped to 799 (write unused LDS tail).
//   LDS layout: [px 0..99][slot^ (px&7)][16B]; read with same XOR.
// ---------------------------------------------------------------------------
__global__ __launch_bounds__(256, 6) void bconv_mfma_kernel(
        const char* __restrict__ S,
        const v4i* __restrict__ wfrag,
        const float2* __restrict__ AB,
        const float* __restrict__ x,
        float* __restrict__ out) {
    __shared__ char Sl[13312];                 // 832 chunks (800 used + clamp)

    const int tid = threadIdx.x;
    const int lane = tid & 63;
    const int wid = tid >> 6;                  // wave = o-tile
    const int l31 = lane & 31, lhi = lane >> 5;

    const int b0 = blockIdx.x;
    const int bid = (b0 & 7) * 392 + (b0 >> 3);
    const int n = bid / 49;
    const int pt = bid - n * 49;
    const int pr = pt / 7, pc = pt - pr * 7;

    // Window origin in padded coords (output patch origin = padded - 1 halo).
    const int Pw = (n * PH_ + pr * 8) * PW_ + pc * 8;

    // ---- Stage 10x10 window -> LDS: per-lane inverse-swizzled global src,
    //      linear LDS dest (glds16: dest = uniform base + lane*16).
    #pragma unroll
    for (int j = 0; j < 13; j++) {
        if ((j & 3) == wid) {
            int chunk = j * 64 + lane;                 // 0..831
            int ck = chunk < 800 ? chunk : 799;        // clamp (dup read)
            int wr = ck / 80;                          // window row 0..9
            int wc = ck - wr * 80;                     // chunk in row 0..79
            int pxr = wc >> 3, s = wc & 7;
            int px = wr * 10 + pxr;                    // window px 0..99
            const char* src = S + (size_t)(Pw + wr * PW_ + pxr) * 128
                                + ((s ^ (px & 7)) << 4);
            glds16(src, &Sl[j * 1024]);
        }
    }

    // Per-chain geometry: chain ch covers patch rows ch*4..ch*4+3, cols 0..7.
    const int lr = l31 >> 3, lc = l31 & 7;     // lane row-in-chain, col
    int pxbase[2];
    #pragma unroll
    for (int ch = 0; ch < 2; ch++)
        pxbase[ch] = (ch * 4 + lr) * 10 + lc;  // window px of tap (0,0)

    __syncthreads();

    v16i acc[2] = {};
    const v4i* wbase = wfrag + (size_t)wid * (9 * 4 * 64) + lane;

    #pragma unroll
    for (int t = 0; t < 9; t++) {
        const int toff = (t / 3) * 10 + (t % 3);
        v4i a[4];
        #pragma unroll
        for (int ks = 0; ks < 4; ks++) a[ks] = wbase[(t * 4 + ks) * 64];
        int px0 = pxbase[0] + toff;
        int px1 = pxbase[1] + toff;
        int A0 = (px0 << 7), k70 = (px0 & 7);
        int A1 = (px1 << 7), k71 = (px1 & 7);
        #pragma unroll
        for (int ks = 0; ks < 4; ks++) {
            const int tslot = 2 * ks + lhi;
            v4i b0 = *(const v4i*)(&Sl[A0 | ((tslot ^ k70) << 4)]);
            v4i b1 = *(const v4i*)(&Sl[A1 | ((tslot ^ k71) << 4)]);
            acc[0] = __builtin_amdgcn_mfma_i32_32x32x32_i8(a[ks], b0, acc[0], 0, 0, 0);
            acc[1] = __builtin_amdgcn_mfma_i32_32x32x32_i8(a[ks], b1, acc[1], 0, 0, 0);
        }
    }

    // Epilogue: out = A*dot + B + x
    const int obase = wid * 32 + 4 * lhi;
    #pragma unroll
    for (int ch = 0; ch < 2; ch++) {
        int prow = pr * 8 + ch * 4 + lr;
        int pcol = pc * 8 + lc;
        unsigned base = (unsigned)n * (unsigned)(C_ * HW_)
                      + (unsigned)(prow * W_ + pcol);
        #pragma unroll
        for (int r = 0; r < 16; r++) {
            int o = obase + (r & 3) + 8 * (r >> 2);
            float2 ab = AB[o];
            unsigned idx = base + (unsigned)o * (unsigned)HW_;
            out[idx] = fmaf(ab.x, (float)acc[ch][r], ab.y) + x[idx];
        }
    }
}

// ---------------------------------------------------------------------------
extern "C" void kernel_launch(void* const* d_in, const int* in_sizes, int n_in,
                              void* d_out, int out_size, void* d_ws, size_t ws_size,
                              hipStream_t stream) {
    const float* x      = (const float*)d_in[0];
    const float* weight = (const float*)d_in[1];
    const float* gamma  = (const float*)d_in[2];
    const float* beta   = (const float*)d_in[3];
    const float* bnmean = (const float*)d_in[4];
    const float* bnvar  = (const float*)d_in[5];
    float* out = (float*)d_out;

    // Layout (r8-proven): S = NPAD*128 = 27,557,888 B, then wfrag, AB.
    char* ws = (char*)d_ws;
    char*   S     = ws;                                   // SBYTES
    v4i*    wfrag = (v4i*)(ws + SBYTES);                  // 147456 B
    float2* AB    = (float2*)(ws + SBYTES + 147456);      // 1024 B

    prep_w_kernel<<<128, 64, 0, stream>>>(weight, gamma, beta, bnmean, bnvar,
                                          wfrag, AB);
    pack_s_kernel<<<NPIX / 64 + 228, 256, 0, stream>>>(x, S);
    bconv_mfma_kernel<<<3136, 256, 0, stream>>>(S, wfrag, AB, x, out);
}